// Round 6
// baseline (50.500 us; speedup 1.0000x reference)
//
#include <hip/hip_runtime.h>
#include <math.h>

#define NN 1024
#define BTH 256
#define NT 16              // NN/64 tile-chunks per row
#define NTILES 136         // NT*(NT+1)/2 upper-triangle 64x64 tiles
#define TBLK 34            // tile blocks per batch (4 waves = 4 tiles each)
#define BPB (TBLK + 1)     // blocks per batch incl. its top-k block

// f(i,j) = softplus(x) - t*x  (t = [ri>rj]), gated by valid = [ri!=rj].
// Identity: sp(x) - t*x = sp((1-2t)x)  =>  symmetric: f(i,j) = f(j,i).
__device__ __forceinline__ float pair_f(float pi, float ri, float pj, float rj) {
    const float x = pi - pj;
    const float y = (ri > rj) ? -x : x;
    const float e = __expf(-fabsf(y));
    const float f = fmaxf(y, 0.0f) + __logf(1.0f + e);
    return (ri != rj) ? f : 0.0f;
}

// Force the returning atomic's result live => compiler emits the returning
// form and a waitcnt before anything later in program order can pass it.
__device__ __forceinline__ void sinkf(float v) { asm volatile("" :: "v"(v)); }

// ---------------------------------------------------------------------------
// ONE worker kernel (plus a 512-B control-block memset in the same graph).
// All cross-block data moves through device-scope atomics only: coherent
// across XCDs with NO __threadfence (the round-5 fence tax).
//   blocks [0,B):       per-batch top-3 + weighted correction + valid count
//   blocks [B,B+34*B):  unweighted upper-triangle 64x64 tiles, one per wave
//   ticket chain:       35th block of a batch -> loss_b; 32nd batch -> out[0]
// ---------------------------------------------------------------------------
__global__ void __launch_bounds__(BTH)
fused_kernel(const float* __restrict__ pred, const float* __restrict__ rel,
             unsigned int* __restrict__ ctrB, unsigned int* __restrict__ ctr2,
             float* __restrict__ acc, float* __restrict__ acc2,
             float* __restrict__ cntv, float* __restrict__ out, int B) {
    const int t = threadIdx.x;
    const int w = t >> 6, l = t & 63;
    const int blk = blockIdx.x;

    __shared__ float  s_p[NN];
    __shared__ float  s_r[NN];
    __shared__ float2 s_seg[4][64];
    __shared__ float  s_rv[3][4];
    __shared__ int    s_ri[3][4];
    __shared__ int    s_hist[4][5];
    __shared__ float  s_red[4];

    int b;
    if (blk < B) {
        // ---------------- top-k path: one block per batch ----------------
        b = blk;
        const size_t base = (size_t)b * NN;
        const float4 p4 = ((const float4*)(pred + base))[t];
        const float4 r4 = ((const float4*)(rel  + base))[t];
        ((float4*)s_p)[t] = p4;
        ((float4*)s_r)[t] = r4;

        // grade histogram via ballots (no LDS atomics)
        for (int g = 0; g < 5; ++g) {
            const float gf = (float)g;
            int c = __popcll(__ballot(r4.x == gf)) + __popcll(__ballot(r4.y == gf))
                  + __popcll(__ballot(r4.z == gf)) + __popcll(__ballot(r4.w == gf));
            if (l == 0) s_hist[w][g] = c;
        }

        // top-3 from registers; tie-break: lower index wins (jax.lax.top_k)
        int w1 = -1, w2 = -1, w3 = -1;
        const int n0 = t * 4;
        for (int k = 0; k < 3; ++k) {
            float bv = -INFINITY;
            int   bi = NN;
            if (n0 + 0 != w1 && n0 + 0 != w2 && p4.x > bv) { bv = p4.x; bi = n0 + 0; }
            if (n0 + 1 != w1 && n0 + 1 != w2 && p4.y > bv) { bv = p4.y; bi = n0 + 1; }
            if (n0 + 2 != w1 && n0 + 2 != w2 && p4.z > bv) { bv = p4.z; bi = n0 + 2; }
            if (n0 + 3 != w1 && n0 + 3 != w2 && p4.w > bv) { bv = p4.w; bi = n0 + 3; }
            for (int off = 32; off > 0; off >>= 1) {
                const float ov = __shfl_xor(bv, off);
                const int   oi = __shfl_xor(bi, off);
                if (ov > bv || (ov == bv && oi < bi)) { bv = ov; bi = oi; }
            }
            if (l == 0) { s_rv[k][w] = bv; s_ri[k][w] = bi; }
            __syncthreads();
            bv = s_rv[k][0]; bi = s_ri[k][0];
            for (int q = 1; q < 4; ++q) {
                const float ov = s_rv[k][q]; const int oi = s_ri[k][q];
                if (ov > bv || (ov == bv && oi < bi)) { bv = ov; bi = oi; }
            }
            if (k == 0) w1 = bi; else if (k == 1) w2 = bi; else w3 = bi;
        }

        // unweighted rowsums over the 3 winners
        float part = 0.0f;
        for (int k = 0; k < 3; ++k) {
            const int row = (k == 0) ? w1 : (k == 1) ? w2 : w3;
            const float pk = s_p[row], rk = s_r[row];
#pragma unroll
            for (int c = 0; c < 4; ++c) {
                const int j = t + c * BTH;
                part += pair_f(pk, rk, s_p[j], s_r[j]);
            }
        }
        for (int off = 32; off > 0; off >>= 1) part += __shfl_down(part, off);
        if (l == 0) s_red[w] = part;
        __syncthreads();
        if (t == 0) {
            const float R = s_red[0] + s_red[1] + s_red[2] + s_red[3];
            const float TT = 2.0f * (pair_f(s_p[w1], s_r[w1], s_p[w2], s_r[w2])
                                   + pair_f(s_p[w1], s_r[w1], s_p[w3], s_r[w3])
                                   + pair_f(s_p[w2], s_r[w2], s_p[w3], s_r[w3]));
            // W = 1 + m_i + m_j + m_i*m_j  =>  weighted = S + 2R + TT
            sinkf(atomicAdd(&acc[b], 2.0f * R + TT));
            int s2 = 0;
            for (int g = 0; g < 5; ++g) {
                const int cg = s_hist[0][g] + s_hist[1][g] + s_hist[2][g] + s_hist[3][g];
                s2 += cg * cg;
            }
            sinkf(atomicExch(&cntv[b], (float)(NN * NN - s2)));
        }
    } else {
        // ---------------- tile path: one wave per 64x64 tile ----------------
        const int idx = blk - B;
        b = idx / TBLK;
        const int L = (idx % TBLK) * 4 + w;     // 0..135
        int rem = L, ti = 0;
        while (rem >= NT - ti) { rem -= NT - ti; ++ti; }
        const int tj = ti + rem;
        const size_t base = (size_t)b * NN;
        const int i0 = ti * 64, j0 = tj * 64;

        const float jp = pred[base + j0 + l];
        const float jr = rel [base + j0 + l];
        // per-wave private LDS segment (wave-lockstep + lgkmcnt, no barrier)
        s_seg[w][l] = make_float2(pred[base + i0 + l], rel[base + i0 + l]);

        float a = 0.0f;
        if (ti != tj) {
#pragma unroll 16
            for (int ii = 0; ii < 64; ++ii) {
                const float2 v = s_seg[w][ii];
                a += pair_f(v.x, v.y, jp, jr);
            }
        } else {
#pragma unroll 16
            for (int ii = 0; ii < 64; ++ii) {
                const float2 v = s_seg[w][ii];
                const float f = pair_f(v.x, v.y, jp, jr);
                a += (l > ii) ? f : 0.0f;       // strict upper triangle
            }
        }
        for (int off = 32; off > 0; off >>= 1) a += __shfl_down(a, off);
        if (l == 0) sinkf(atomicAdd(&acc[b], 2.0f * a));   // both pair orders
    }

    // __syncthreads drains vmcnt: all this block's data atomics are complete
    // (globally coherent) before its ticket is taken.
    __syncthreads();
    if (t == 0) {
        const unsigned int old = atomicAdd(&ctrB[b], 1u);
        if (old == (unsigned int)(BPB - 1)) {
            // batch-winner: all 35 blocks of batch b have contributed
            const float s = atomicAdd(&acc[b], 0.0f);    // coherent read
            const float c = atomicAdd(&cntv[b], 0.0f);
            sinkf(atomicAdd(acc2, s / (c + 1e-8f) * (1.0f / (float)B)));
            const unsigned int o2 = atomicAdd(ctr2, 1u);
            if (o2 == (unsigned int)(B - 1)) {
                out[0] = atomicAdd(acc2, 0.0f);          // final result
            }
        }
    }
}

extern "C" void kernel_launch(void* const* d_in, const int* in_sizes, int n_in,
                              void* d_out, int out_size, void* d_ws, size_t ws_size,
                              hipStream_t stream) {
    const float* pred = (const float*)d_in[0];
    const float* rel  = (const float*)d_in[1];
    float* out = (float*)d_out;

    const int B = in_sizes[0] / NN;  // 32

    // control block (memset to 0 each launch, 512 B):
    //   [0]   ctrB[32]   batch tickets
    //   [128] ctr2       global ticket
    //   [192] acc[32]    per-batch weighted sums
    //   [320] acc2       final accumulator
    //   [384] cntv[32]   per-batch valid-pair counts
    unsigned int* ctrB = (unsigned int*)d_ws;
    unsigned int* ctr2 = (unsigned int*)((char*)d_ws + 128);
    float* acc  = (float*)((char*)d_ws + 192);
    float* acc2 = (float*)((char*)d_ws + 320);
    float* cntv = (float*)((char*)d_ws + 384);

    hipMemsetAsync(d_ws, 0, 512, stream);
    fused_kernel<<<B + TBLK * B, BTH, 0, stream>>>(pred, rel, ctrB, ctr2,
                                                   acc, acc2, cntv, out, B);
}

// Round 7
// 25.886 us; speedup vs baseline: 1.9509x; 1.9509x over previous
//
#include <hip/hip_runtime.h>
#include <math.h>

#define NN 1024
#define BTH 256
#define NT 16              // NN/64 tile-chunks per row
#define NTILES 136         // NT*(NT+1)/2 upper-triangle 64x64 tiles
#define TBLK 34            // tile blocks per batch (4 waves = 4 tiles each)
#define BPB (TBLK + 1)     // blocks per batch incl. its top-k block
#define LINE 512           // per-batch control-slot stride (bytes)

// f(i,j) = softplus(x) - t*x  (t = [ri>rj]), gated by valid = [ri!=rj].
// Identity: sp(x) - t*x = sp((1-2t)x)  =>  symmetric: f(i,j) = f(j,i).
__device__ __forceinline__ float pair_f(float pi, float ri, float pj, float rj) {
    const float x = pi - pj;
    const float y = (ri > rj) ? -x : x;
    const float e = __expf(-fabsf(y));
    const float f = fmaxf(y, 0.0f) + __logf(1.0f + e);
    return (ri != rj) ? f : 0.0f;
}

// Keep a returning atomic's result live -> compiler emits waitcnt before the
// asm, ordering it ahead of any later vmem op from this thread.
__device__ __forceinline__ void sinkf(float v) { asm volatile("" :: "v"(v)); }

// ---------------------------------------------------------------------------
// ONE worker kernel (+ 16.9 KB control-block memset in the same graph).
// Cross-block data moves ONLY via device-scope atomics (coherent across XCDs,
// no fences). Round-6 lesson: contended SAME-LINE atomics cost ~60ns each and
// serialize -> every per-batch counter/accumulator gets its OWN 128B line.
//   blocks [0,B):       per-batch top-3 + weighted correction + valid count
//   blocks [B,B+34*B):  unweighted upper-triangle 64x64 tiles, one per wave
//   ticket chain:       35th block of batch b -> loss_b; 32nd batch -> out[0]
// Ordering: data atomics (non-returning) -> __syncthreads (vmcnt(0) drain,
// atomics performed at coherence point) -> ticket atomic (returning).
// ---------------------------------------------------------------------------
__global__ void __launch_bounds__(BTH)
fused_kernel(const float* __restrict__ pred, const float* __restrict__ rel,
             char* __restrict__ ws, float* __restrict__ out, int B) {
    const int t = threadIdx.x;
    const int w = t >> 6, l = t & 63;
    const int blk = blockIdx.x;

    __shared__ float  s_p[NN];
    __shared__ float  s_r[NN];
    __shared__ float2 s_seg[4][64];
    __shared__ float  s_rv[3][4];
    __shared__ int    s_ri[3][4];
    __shared__ int    s_hist[4][5];
    __shared__ float  s_red[4];

    int b;
    if (blk < B) {
        // ---------------- top-k path: one block per batch ----------------
        b = blk;
        const size_t base = (size_t)b * NN;
        const float4 p4 = ((const float4*)(pred + base))[t];
        const float4 r4 = ((const float4*)(rel  + base))[t];
        ((float4*)s_p)[t] = p4;
        ((float4*)s_r)[t] = r4;

        // grade histogram via ballots (no LDS atomics)
        for (int g = 0; g < 5; ++g) {
            const float gf = (float)g;
            int c = __popcll(__ballot(r4.x == gf)) + __popcll(__ballot(r4.y == gf))
                  + __popcll(__ballot(r4.z == gf)) + __popcll(__ballot(r4.w == gf));
            if (l == 0) s_hist[w][g] = c;
        }

        // top-3 from registers; tie-break: lower index wins (jax.lax.top_k)
        int w1 = -1, w2 = -1, w3 = -1;
        const int n0 = t * 4;
        for (int k = 0; k < 3; ++k) {
            float bv = -INFINITY;
            int   bi = NN;
            if (n0 + 0 != w1 && n0 + 0 != w2 && p4.x > bv) { bv = p4.x; bi = n0 + 0; }
            if (n0 + 1 != w1 && n0 + 1 != w2 && p4.y > bv) { bv = p4.y; bi = n0 + 1; }
            if (n0 + 2 != w1 && n0 + 2 != w2 && p4.z > bv) { bv = p4.z; bi = n0 + 2; }
            if (n0 + 3 != w1 && n0 + 3 != w2 && p4.w > bv) { bv = p4.w; bi = n0 + 3; }
            for (int off = 32; off > 0; off >>= 1) {
                const float ov = __shfl_xor(bv, off);
                const int   oi = __shfl_xor(bi, off);
                if (ov > bv || (ov == bv && oi < bi)) { bv = ov; bi = oi; }
            }
            if (l == 0) { s_rv[k][w] = bv; s_ri[k][w] = bi; }
            __syncthreads();
            bv = s_rv[k][0]; bi = s_ri[k][0];
            for (int q = 1; q < 4; ++q) {
                const float ov = s_rv[k][q]; const int oi = s_ri[k][q];
                if (ov > bv || (ov == bv && oi < bi)) { bv = ov; bi = oi; }
            }
            if (k == 0) w1 = bi; else if (k == 1) w2 = bi; else w3 = bi;
        }

        // unweighted rowsums over the 3 winners
        float part = 0.0f;
        for (int k = 0; k < 3; ++k) {
            const int row = (k == 0) ? w1 : (k == 1) ? w2 : w3;
            const float pk = s_p[row], rk = s_r[row];
#pragma unroll
            for (int c = 0; c < 4; ++c) {
                const int j = t + c * BTH;
                part += pair_f(pk, rk, s_p[j], s_r[j]);
            }
        }
        for (int off = 32; off > 0; off >>= 1) part += __shfl_down(part, off);
        if (l == 0) s_red[w] = part;
        __syncthreads();
        if (t == 0) {
            const float R = s_red[0] + s_red[1] + s_red[2] + s_red[3];
            const float TT = 2.0f * (pair_f(s_p[w1], s_r[w1], s_p[w2], s_r[w2])
                                   + pair_f(s_p[w1], s_r[w1], s_p[w3], s_r[w3])
                                   + pair_f(s_p[w2], s_r[w2], s_p[w3], s_r[w3]));
            // W = 1 + m_i + m_j + m_i*m_j  =>  weighted = S + 2R + TT
            atomicAdd((float*)(ws + (size_t)b * LINE), 2.0f * R + TT);  // no return
            int s2 = 0;
            for (int g = 0; g < 5; ++g) {
                const int cg = s_hist[0][g] + s_hist[1][g] + s_hist[2][g] + s_hist[3][g];
                s2 += cg * cg;
            }
            atomicExch((float*)(ws + (size_t)b * LINE + 128),
                       (float)(NN * NN - s2));                          // no return
        }
    } else {
        // ---------------- tile path: one wave per 64x64 tile ----------------
        const int idx = blk - B;
        b = idx / TBLK;
        const int L = (idx % TBLK) * 4 + w;     // 0..135
        int rem = L, ti = 0;
        while (rem >= NT - ti) { rem -= NT - ti; ++ti; }
        const int tj = ti + rem;
        const size_t base = (size_t)b * NN;
        const int i0 = ti * 64, j0 = tj * 64;

        const float jp = pred[base + j0 + l];
        const float jr = rel [base + j0 + l];
        // per-wave private LDS segment (wave-lockstep + lgkmcnt, no barrier)
        s_seg[w][l] = make_float2(pred[base + i0 + l], rel[base + i0 + l]);

        float a = 0.0f;
        if (ti != tj) {
#pragma unroll 16
            for (int ii = 0; ii < 64; ++ii) {
                const float2 v = s_seg[w][ii];
                a += pair_f(v.x, v.y, jp, jr);
            }
        } else {
#pragma unroll 16
            for (int ii = 0; ii < 64; ++ii) {
                const float2 v = s_seg[w][ii];
                const float f = pair_f(v.x, v.y, jp, jr);
                a += (l > ii) ? f : 0.0f;       // strict upper triangle
            }
        }
        for (int off = 32; off > 0; off >>= 1) a += __shfl_down(a, off);
        if (l == 0)
            atomicAdd((float*)(ws + (size_t)b * LINE), 2.0f * a);       // no return
    }

    // __syncthreads drains vmcnt: this block's data atomics are performed at
    // the coherence point before its ticket is taken.
    __syncthreads();
    if (t == 0) {
        unsigned int* ctr_b = (unsigned int*)(ws + (size_t)b * LINE + 256);
        const unsigned int old = atomicAdd(ctr_b, 1u);
        if (old == (unsigned int)(BPB - 1)) {
            // batch-winner: all 35 blocks of batch b have contributed
            float* acc_b  = (float*)(ws + (size_t)b * LINE);
            float* cntv_b = (float*)(ws + (size_t)b * LINE + 128);
            const float s = atomicAdd(acc_b, 0.0f);      // coherent read
            const float c = atomicAdd(cntv_b, 0.0f);
            float* accG = (float*)(ws + (size_t)B * LINE);
            unsigned int* ctrG = (unsigned int*)(ws + (size_t)B * LINE + 128);
            sinkf(atomicAdd(accG, s / (c + 1e-8f) * (1.0f / (float)B)));
            const unsigned int o2 = atomicAdd(ctrG, 1u);
            if (o2 == (unsigned int)(B - 1)) {
                out[0] = atomicAdd(accG, 0.0f);          // final result
            }
        }
    }
}

extern "C" void kernel_launch(void* const* d_in, const int* in_sizes, int n_in,
                              void* d_out, int out_size, void* d_ws, size_t ws_size,
                              hipStream_t stream) {
    const float* pred = (const float*)d_in[0];
    const float* rel  = (const float*)d_in[1];
    float* out = (float*)d_out;

    const int B = in_sizes[0] / NN;  // 32

    // Control block: one 512-B slot per batch (acc@+0, cntv@+128, ctr@+256,
    // each on its own 128-B cache line) + one global slot (accG@+0, ctrG@+128).
    const size_t ctl_bytes = (size_t)(B + 1) * LINE;   // 16896
    hipMemsetAsync(d_ws, 0, ctl_bytes, stream);
    fused_kernel<<<B + TBLK * B, BTH, 0, stream>>>(pred, rel, (char*)d_ws, out, B);
}

// Round 9
// 21.617 us; speedup vs baseline: 2.3361x; 1.1975x over previous
//
#include <hip/hip_runtime.h>
#include <math.h>

#define NN 1024
#define BTH 256
#define NT 16              // NN/64 tile-chunks per row
#define NTILES 136         // NT*(NT+1)/2 upper-triangle 64x64 tiles
#define TBLK 34            // tile blocks per batch (4 waves = 4 tiles each)
#define BPB (TBLK + 1)     // blocks per batch incl. its top-k block

// ws byte offsets. All data slots are OVERWRITTEN (atomicExch) every launch
// before any read -> no reset needed, immune to initial garbage/poison.
//   slotT[32][136] f32 @ 0       per-tile partial sums
//   slotC[32]      f32 @ 17408   per-batch top-k correction
//   slotV[32]      f32 @ 17536   per-batch valid-pair count
//   lossS[32]      f32 @ 17664   per-batch loss
//   ctrB[b]        u32 @ 17792 + b*128   (own cache line each)
//   ctrG           u32 @ 21888
// Tickets use atomicInc wraparound (LIMIT = P-1): counter cycles 0..P-1 and
// ANY start value >= P-1 (0xAA poison = 2.8e9, or the steady-state residue
// P-1 left by the previous launch) wraps to 0 at the first arrival, so the
// winner (old == P-2) is exactly the LAST arrival -- round-8's modulo ticket
// fired at the wrong arrival for poisoned starts and read unwritten slots.
#define OFF_T 0
#define OFF_C 17408
#define OFF_V 17536
#define OFF_L 17664
#define OFF_CB 17792
#define OFF_CG 21888

// f(i,j) = softplus(x) - t*x  (t = [ri>rj]), gated by valid = [ri!=rj].
// Identity: sp(x) - t*x = sp((1-2t)x)  =>  symmetric: f(i,j) = f(j,i).
__device__ __forceinline__ float pair_f(float pi, float ri, float pj, float rj) {
    const float x = pi - pj;
    const float y = (ri > rj) ? -x : x;
    const float e = __expf(-fabsf(y));
    const float f = fmaxf(y, 0.0f) + __logf(1.0f + e);
    return (ri != rj) ? f : 0.0f;
}

// Keep a returning atomic's result live -> compiler must waitcnt before the
// asm, ordering it ahead of any later vmem op in program order.
__device__ __forceinline__ void sinkf(float v) { asm volatile("" :: "v"(v)); }

// ---------------------------------------------------------------------------
// ONE dispatch, nothing else. Cross-block data via device-scope atomics only
// (coherent across XCDs, no fences). Per-batch counters on private 128-B
// lines (round-6 lesson: same-line contended atomics serialize ~60ns each).
// Ordering: overwrite-slot atomics -> __syncthreads (vmcnt(0) drain: slots
// performed at the coherence point) -> ticket atomicInc.
// ---------------------------------------------------------------------------
__global__ void __launch_bounds__(BTH)
fused_kernel(const float* __restrict__ pred, const float* __restrict__ rel,
             char* __restrict__ ws, float* __restrict__ out, int B) {
    const int t = threadIdx.x;
    const int w = t >> 6, l = t & 63;
    const int blk = blockIdx.x;

    __shared__ float  s_p[NN];
    __shared__ float  s_r[NN];
    __shared__ float2 s_seg[4][64];
    __shared__ float  s_rv[3][4];
    __shared__ int    s_ri[3][4];
    __shared__ int    s_hist[4][5];
    __shared__ float  s_red[4];
    __shared__ float  s_corr, s_cnt;
    __shared__ int    s_flag, s_flag2;

    float* slotT = (float*)(ws + OFF_T);
    float* slotC = (float*)(ws + OFF_C);
    float* slotV = (float*)(ws + OFF_V);
    float* lossS = (float*)(ws + OFF_L);

    int b;
    if (blk < B) {
        // ---------------- top-k path: one block per batch ----------------
        b = blk;
        const size_t base = (size_t)b * NN;
        const float4 p4 = ((const float4*)(pred + base))[t];
        const float4 r4 = ((const float4*)(rel  + base))[t];
        ((float4*)s_p)[t] = p4;
        ((float4*)s_r)[t] = r4;

        // grade histogram via ballots (no LDS atomics)
        for (int g = 0; g < 5; ++g) {
            const float gf = (float)g;
            int c = __popcll(__ballot(r4.x == gf)) + __popcll(__ballot(r4.y == gf))
                  + __popcll(__ballot(r4.z == gf)) + __popcll(__ballot(r4.w == gf));
            if (l == 0) s_hist[w][g] = c;
        }

        // top-3 from registers; tie-break: lower index wins (jax.lax.top_k)
        int w1 = -1, w2 = -1, w3 = -1;
        const int n0 = t * 4;
        for (int k = 0; k < 3; ++k) {
            float bv = -INFINITY;
            int   bi = NN;
            if (n0 + 0 != w1 && n0 + 0 != w2 && p4.x > bv) { bv = p4.x; bi = n0 + 0; }
            if (n0 + 1 != w1 && n0 + 1 != w2 && p4.y > bv) { bv = p4.y; bi = n0 + 1; }
            if (n0 + 2 != w1 && n0 + 2 != w2 && p4.z > bv) { bv = p4.z; bi = n0 + 2; }
            if (n0 + 3 != w1 && n0 + 3 != w2 && p4.w > bv) { bv = p4.w; bi = n0 + 3; }
            for (int off = 32; off > 0; off >>= 1) {
                const float ov = __shfl_xor(bv, off);
                const int   oi = __shfl_xor(bi, off);
                if (ov > bv || (ov == bv && oi < bi)) { bv = ov; bi = oi; }
            }
            if (l == 0) { s_rv[k][w] = bv; s_ri[k][w] = bi; }
            __syncthreads();
            bv = s_rv[k][0]; bi = s_ri[k][0];
            for (int q = 1; q < 4; ++q) {
                const float ov = s_rv[k][q]; const int oi = s_ri[k][q];
                if (ov > bv || (ov == bv && oi < bi)) { bv = ov; bi = oi; }
            }
            if (k == 0) w1 = bi; else if (k == 1) w2 = bi; else w3 = bi;
        }

        // unweighted rowsums over the 3 winners
        float part = 0.0f;
        for (int k = 0; k < 3; ++k) {
            const int row = (k == 0) ? w1 : (k == 1) ? w2 : w3;
            const float pk = s_p[row], rk = s_r[row];
#pragma unroll
            for (int c = 0; c < 4; ++c) {
                const int j = t + c * BTH;
                part += pair_f(pk, rk, s_p[j], s_r[j]);
            }
        }
        for (int off = 32; off > 0; off >>= 1) part += __shfl_down(part, off);
        if (l == 0) s_red[w] = part;
        __syncthreads();
        if (t == 0) {
            const float R = s_red[0] + s_red[1] + s_red[2] + s_red[3];
            const float TT = 2.0f * (pair_f(s_p[w1], s_r[w1], s_p[w2], s_r[w2])
                                   + pair_f(s_p[w1], s_r[w1], s_p[w3], s_r[w3])
                                   + pair_f(s_p[w2], s_r[w2], s_p[w3], s_r[w3]));
            // W = 1 + m_i + m_j + m_i*m_j  =>  weighted = S + 2R + TT
            atomicExch(&slotC[b], 2.0f * R + TT);                 // overwrite
            int s2 = 0;
            for (int g = 0; g < 5; ++g) {
                const int cg = s_hist[0][g] + s_hist[1][g] + s_hist[2][g] + s_hist[3][g];
                s2 += cg * cg;
            }
            atomicExch(&slotV[b], (float)(NN * NN - s2));         // overwrite
        }
    } else {
        // ---------------- tile path: one wave per 64x64 tile ----------------
        const int idx = blk - B;
        b = idx / TBLK;
        const int L = (idx % TBLK) * 4 + w;     // 0..135
        int rem = L, ti = 0;
        while (rem >= NT - ti) { rem -= NT - ti; ++ti; }
        const int tj = ti + rem;
        const size_t base = (size_t)b * NN;
        const int i0 = ti * 64, j0 = tj * 64;

        const float jp = pred[base + j0 + l];
        const float jr = rel [base + j0 + l];
        // per-wave private LDS segment (wave-lockstep + lgkmcnt, no barrier)
        s_seg[w][l] = make_float2(pred[base + i0 + l], rel[base + i0 + l]);

        float a = 0.0f;
        if (ti != tj) {
#pragma unroll 16
            for (int ii = 0; ii < 64; ++ii) {
                const float2 v = s_seg[w][ii];
                a += pair_f(v.x, v.y, jp, jr);
            }
        } else {
#pragma unroll 16
            for (int ii = 0; ii < 64; ++ii) {
                const float2 v = s_seg[w][ii];
                const float f = pair_f(v.x, v.y, jp, jr);
                a += (l > ii) ? f : 0.0f;       // strict upper triangle
            }
        }
        for (int off = 32; off > 0; off >>= 1) a += __shfl_down(a, off);
        if (l == 0)
            atomicExch(&slotT[(size_t)b * NTILES + L], 2.0f * a); // overwrite
    }

    // __syncthreads drains vmcnt: this block's slot writes are performed at
    // the coherence point before its ticket is taken.
    __syncthreads();
    if (t == 0) {
        unsigned int* ctr_b = (unsigned int*)(ws + OFF_CB + (size_t)b * 128);
        // cycle 0..BPB-1; any start >= BPB-1 wraps to 0 at first arrival,
        // so old == BPB-2 identifies the LAST (35th) arrival; leaves BPB-1.
        const unsigned int old = atomicInc(ctr_b, (unsigned int)(BPB - 1));
        s_flag = (old == (unsigned int)(BPB - 2)) ? 1 : 0;
    }
    __syncthreads();
    if (!s_flag) return;                         // block-uniform

    // ------------- batch winner: all 35 blocks of batch b are done -------------
    {
        float v = 0.0f;
        if (t < NTILES)            v = atomicAdd(&slotT[(size_t)b * NTILES + t], 0.0f);
        else if (t == NTILES)      s_corr = atomicAdd(&slotC[b], 0.0f);
        else if (t == NTILES + 1)  s_cnt  = atomicAdd(&slotV[b], 0.0f);
        for (int off = 32; off > 0; off >>= 1) v += __shfl_down(v, off);
        if (l == 0) s_red[w] = v;
        __syncthreads();
        if (t == 0) {
            const float S = s_red[0] + s_red[1] + s_red[2] + s_red[3];
            const float loss_b = (S + s_corr) / (s_cnt + 1e-8f);
            sinkf(atomicExch(&lossS[b], loss_b));        // ordered before ticket
            unsigned int* ctrG = (unsigned int*)(ws + OFF_CG);
            const unsigned int o2 = atomicInc(ctrG, (unsigned int)(B - 1));
            s_flag2 = (o2 == (unsigned int)(B - 2)) ? 1 : 0;
        }
        __syncthreads();
        if (s_flag2 && w == 0) {
            // ------------- global winner: all 32 batch losses written -------------
            float u = (l < B) ? atomicAdd(&lossS[l], 0.0f) : 0.0f;
            for (int off = 32; off > 0; off >>= 1) u += __shfl_down(u, off);
            if (l == 0) out[0] = u / (float)B;
        }
    }
}

extern "C" void kernel_launch(void* const* d_in, const int* in_sizes, int n_in,
                              void* d_out, int out_size, void* d_ws, size_t ws_size,
                              hipStream_t stream) {
    const float* pred = (const float*)d_in[0];
    const float* rel  = (const float*)d_in[1];
    float* out = (float*)d_out;

    const int B = in_sizes[0] / NN;  // 32

    fused_kernel<<<B + TBLK * B, BTH, 0, stream>>>(pred, rel, (char*)d_ws, out, B);
}